// Round 4
// baseline (311.325 us; speedup 1.0000x reference)
//
#include <hip/hip_runtime.h>

#define NB 8        // batches
#define NC 128      // channels
#define NH 16       // hidden
#define BN_EPS 1e-3f

// ---------------------------------------------------------------------------
// Zero the segment-sum accumulator. Must be a kernel (not hipMemsetAsync):
// memset on the capturing stream was not replayed inside the graph, so sums
// accumulated across timed replays (round-2 post-timing divergence).
// ---------------------------------------------------------------------------
__global__ __launch_bounds__(256) void k_zero(float* __restrict__ sums) {
    sums[threadIdx.x + blockIdx.x * 256] = 0.f;   // grid covers NB*NC = 1024
}

// ---------------------------------------------------------------------------
// Pass 1: segment sum of (feat3 + feat5) over sorted batch_idx.
// Block = 256 threads: 8 rows per iteration, each row covered by 32 lanes
// doing one float4 (128 cols). batch_idx is sorted, so each thread's batch is
// non-decreasing across its grid-stride walk: keep ONE float4 accumulator +
// current batch id, flush to LDS (atomicAdd) only when the batch changes
// (<= 7 flushes/thread). Final merge: 1024 global atomics per block.
// ---------------------------------------------------------------------------
__global__ __launch_bounds__(256) void k_segsum(const float* __restrict__ f3,
                                                const float* __restrict__ f5,
                                                const int* __restrict__ bidx,
                                                float* __restrict__ sums,  // [NB][NC], zeroed by k_zero
                                                int N) {
    __shared__ float s[NB][NC];
    for (int i = threadIdx.x; i < NB * NC; i += 256) ((float*)s)[i] = 0.f;
    __syncthreads();

    const int lr = threadIdx.x >> 5;   // row-in-block 0..7
    const int cv = threadIdx.x & 31;   // float4 index within row (col = cv*4)
    const float4* __restrict__ f3v = (const float4*)f3;
    const float4* __restrict__ f5v = (const float4*)f5;

    float4 acc = make_float4(0.f, 0.f, 0.f, 0.f);
    int cur = -1;
    const int stride = gridDim.x * 8;
    for (int row = blockIdx.x * 8 + lr; row < N; row += stride) {
        const int b = bidx[row];
        if (b != cur) {
            if (cur >= 0) {
                atomicAdd(&s[cur][cv * 4 + 0], acc.x);
                atomicAdd(&s[cur][cv * 4 + 1], acc.y);
                atomicAdd(&s[cur][cv * 4 + 2], acc.z);
                atomicAdd(&s[cur][cv * 4 + 3], acc.w);
            }
            acc = make_float4(0.f, 0.f, 0.f, 0.f);
            cur = b;
        }
        const float4 a = f3v[(size_t)row * 32 + cv];
        const float4 c = f5v[(size_t)row * 32 + cv];
        acc.x += a.x + c.x;
        acc.y += a.y + c.y;
        acc.z += a.z + c.z;
        acc.w += a.w + c.w;
    }
    if (cur >= 0) {
        atomicAdd(&s[cur][cv * 4 + 0], acc.x);
        atomicAdd(&s[cur][cv * 4 + 1], acc.y);
        atomicAdd(&s[cur][cv * 4 + 2], acc.z);
        atomicAdd(&s[cur][cv * 4 + 3], acc.w);
    }
    __syncthreads();
    for (int i = threadIdx.x; i < NB * NC; i += 256) {
        const float v = ((float*)s)[i];
        if (v != 0.f) atomicAdd(&sums[i], v);
    }
}

// ---------------------------------------------------------------------------
// Tiny single-block kernel: counts (binary search on sorted batch_idx),
// feat_s = sums/count, squeeze Linear + BN + ReLU, excitation, 2-way softmax.
// Writes att[0..1023] = a3, att[1024..2047] = a5.
// ---------------------------------------------------------------------------
__global__ __launch_bounds__(256) void k_attn(const float* __restrict__ sums,
                                              const int* __restrict__ bidx,
                                              const float* __restrict__ w_sq,   // [NC][NH]
                                              const float* __restrict__ gamma,
                                              const float* __restrict__ beta,
                                              const float* __restrict__ mean,
                                              const float* __restrict__ var,
                                              const float* __restrict__ wex3,   // [NH][NC]
                                              const float* __restrict__ wex5,   // [NH][NC]
                                              float* __restrict__ att,          // [2][NB][NC]
                                              int N) {
    __shared__ float fs[NB][NC];
    __shared__ float fz[NB][NH];
    __shared__ float rcnt[NB];

    if (threadIdx.x < NB) {
        const int t = (int)threadIdx.x;
        int lo0, lo1;
        {   // first index with bidx >= t
            int lo = 0, hi = N;
            while (lo < hi) { int m = (lo + hi) >> 1; if (bidx[m] < t) lo = m + 1; else hi = m; }
            lo0 = lo;
        }
        {   // first index with bidx >= t+1
            int lo = 0, hi = N;
            while (lo < hi) { int m = (lo + hi) >> 1; if (bidx[m] < t + 1) lo = m + 1; else hi = m; }
            lo1 = lo;
        }
        rcnt[t] = 1.0f / (float)(lo1 - lo0);
    }
    __syncthreads();

    for (int i = threadIdx.x; i < NB * NC; i += 256) {
        const int b = i >> 7;
        ((float*)fs)[i] = sums[i] * rcnt[b];
    }
    __syncthreads();

    if (threadIdx.x < NB * NH) {
        const int b = threadIdx.x >> 4;
        const int h = threadIdx.x & 15;
        float z = 0.f;
        #pragma unroll 8
        for (int c = 0; c < NC; ++c) z += fs[b][c] * w_sq[c * NH + h];
        z = (z - mean[h]) * rsqrtf(var[h] + BN_EPS) * gamma[h] + beta[h];
        fz[b][h] = z > 0.f ? z : 0.f;
    }
    __syncthreads();

    for (int i = threadIdx.x; i < NB * NC; i += 256) {
        const int b = i >> 7;
        const int c = i & 127;
        float e3 = 0.f, e5 = 0.f;
        #pragma unroll
        for (int h = 0; h < NH; ++h) {
            const float zz = fz[b][h];
            e3 += zz * wex3[h * NC + c];
            e5 += zz * wex5[h * NC + c];
        }
        const float a3 = 1.f / (1.f + expf(e5 - e3));  // softmax over the 2 branches
        att[i] = a3;
        att[NB * NC + i] = 1.f - a3;
    }
}

// ---------------------------------------------------------------------------
// Pass 2: out = feat3 * a3[b] + feat5 * a5[b], attention table staged in LDS.
// ---------------------------------------------------------------------------
__global__ __launch_bounds__(256) void k_combine(const float* __restrict__ f3,
                                                 const float* __restrict__ f5,
                                                 const int* __restrict__ bidx,
                                                 const float* __restrict__ att,
                                                 float* __restrict__ out,
                                                 int N) {
    __shared__ float a3[NB][NC];
    __shared__ float a5[NB][NC];
    for (int i = threadIdx.x; i < NB * NC; i += 256) {
        ((float*)a3)[i] = att[i];
        ((float*)a5)[i] = att[NB * NC + i];
    }
    __syncthreads();

    const int lr = threadIdx.x >> 5;
    const int cv = threadIdx.x & 31;
    const float4* __restrict__ f3v = (const float4*)f3;
    const float4* __restrict__ f5v = (const float4*)f5;
    float4* __restrict__ outv = (float4*)out;

    const int stride = gridDim.x * 8;
    for (int row = blockIdx.x * 8 + lr; row < N; row += stride) {
        const int b = bidx[row];
        const float4 v3 = f3v[(size_t)row * 32 + cv];
        const float4 v5 = f5v[(size_t)row * 32 + cv];
        const float4 w3 = ((const float4*)a3[b])[cv];
        const float4 w5 = ((const float4*)a5[b])[cv];
        float4 o;
        o.x = v3.x * w3.x + v5.x * w5.x;
        o.y = v3.y * w3.y + v5.y * w5.y;
        o.z = v3.z * w3.z + v5.z * w5.z;
        o.w = v3.w * w3.w + v5.w * w5.w;
        outv[(size_t)row * 32 + cv] = o;
    }
}

extern "C" void kernel_launch(void* const* d_in, const int* in_sizes, int n_in,
                              void* d_out, int out_size, void* d_ws, size_t ws_size,
                              hipStream_t stream) {
    const float* f3    = (const float*)d_in[0];
    const float* f5    = (const float*)d_in[1];
    const int*   bidx  = (const int*)d_in[2];
    const float* w_sq  = (const float*)d_in[3];
    const float* gamma = (const float*)d_in[4];
    const float* beta  = (const float*)d_in[5];
    const float* mean  = (const float*)d_in[6];
    const float* var   = (const float*)d_in[7];
    const float* wex3  = (const float*)d_in[8];
    const float* wex5  = (const float*)d_in[9];
    float* out = (float*)d_out;

    const int N = in_sizes[2];           // 500000 rows

    float* sums = (float*)d_ws;          // [NB][NC]
    float* att  = sums + NB * NC;        // [2][NB][NC]

    const int nblk = 2048;               // fills 256 CUs * 8 blocks/CU

    // Zero sums via a KERNEL so it is part of the captured graph on every
    // replay (hipMemsetAsync was not replayed -> round-2 accumulation bug).
    k_zero<<<(NB * NC) / 256, 256, 0, stream>>>(sums);
    k_segsum<<<nblk, 256, 0, stream>>>(f3, f5, bidx, sums, N);
    k_attn<<<1, 256, 0, stream>>>(sums, bidx, w_sq, gamma, beta, mean, var, wex3, wex5, att, N);
    k_combine<<<nblk, 256, 0, stream>>>(f3, f5, bidx, att, out, N);
}

// Round 5
// 306.745 us; speedup vs baseline: 1.0149x; 1.0149x over previous
//
#include <hip/hip_runtime.h>

#define NB 8        // batches
#define NC 128      // channels
#define NH 16       // hidden
#define BN_EPS 1e-3f
#define NBLK 2048   // grid for the two streaming kernels

// ---------------------------------------------------------------------------
// Prep (1 block): zero the segment-sum accumulator (must be a kernel, not
// hipMemsetAsync — memset wasn't replayed in the captured graph, round-2 bug)
// and compute the 9 segment boundaries of the sorted batch_idx by binary
// search. bounds[t] = first row with bidx >= t; bounds[8] = N.
// ---------------------------------------------------------------------------
__global__ __launch_bounds__(256) void k_prep(const int* __restrict__ bidx,
                                              float* __restrict__ sums,
                                              int* __restrict__ bounds,
                                              int N) {
    for (int i = threadIdx.x; i < NB * NC; i += 256) sums[i] = 0.f;
    if (threadIdx.x <= NB) {
        const int t = (int)threadIdx.x;
        int lo = 0, hi = N;
        while (lo < hi) { int m = (lo + hi) >> 1; if (bidx[m] < t) lo = m + 1; else hi = m; }
        bounds[t] = lo;
    }
}

// ---------------------------------------------------------------------------
// Pass 1: segment sum of (feat3 + feat5), boundary-driven.
// Per segment: wave-uniform loop bounds, no per-row bidx load, no
// data-dependent branch (round-4 profile: the branchy run-tracking version
// ran at 2.9 TB/s effective vs 5.7 for the branch-free combine loop).
// One LDS-atomic flush per segment under uniform control flow, then a single
// global atomic merge per block.
// ---------------------------------------------------------------------------
__global__ __launch_bounds__(256) void k_segsum(const float4* __restrict__ f3v,
                                                const float4* __restrict__ f5v,
                                                const int* __restrict__ bounds,
                                                float* __restrict__ sums) {
    __shared__ float s[NB][NC];
    __shared__ int sb[NB + 1];
    if (threadIdx.x <= NB) sb[threadIdx.x] = bounds[threadIdx.x];
    for (int i = threadIdx.x; i < NB * NC; i += 256) ((float*)s)[i] = 0.f;
    __syncthreads();

    const int lr = threadIdx.x >> 5;          // row-in-block 0..7
    const int cv = threadIdx.x & 31;          // float4 index within the row
    const int base = (int)blockIdx.x * 8 + lr;
    const int stride = NBLK * 8;

    for (int seg = 0; seg < NB; ++seg) {
        const int hi = sb[seg + 1];
        float4 acc = make_float4(0.f, 0.f, 0.f, 0.f);
        for (int row = sb[seg] + base; row < hi; row += stride) {
            const float4 a = f3v[(size_t)row * 32 + cv];
            const float4 c = f5v[(size_t)row * 32 + cv];
            acc.x += a.x + c.x;
            acc.y += a.y + c.y;
            acc.z += a.z + c.z;
            acc.w += a.w + c.w;
        }
        atomicAdd(&s[seg][cv * 4 + 0], acc.x);
        atomicAdd(&s[seg][cv * 4 + 1], acc.y);
        atomicAdd(&s[seg][cv * 4 + 2], acc.z);
        atomicAdd(&s[seg][cv * 4 + 3], acc.w);
    }
    __syncthreads();
    for (int i = threadIdx.x; i < NB * NC; i += 256)
        atomicAdd(&sums[i], ((float*)s)[i]);
}

// ---------------------------------------------------------------------------
// Tiny single-block kernel: feat_s = sums/count (counts from bounds),
// squeeze Linear + BN + ReLU, excitation, 2-way softmax.
// Writes att[0..1023] = a3, att[1024..2047] = a5.
// ---------------------------------------------------------------------------
__global__ __launch_bounds__(256) void k_attn(const float* __restrict__ sums,
                                              const int* __restrict__ bounds,
                                              const float* __restrict__ w_sq,   // [NC][NH]
                                              const float* __restrict__ gamma,
                                              const float* __restrict__ beta,
                                              const float* __restrict__ mean,
                                              const float* __restrict__ var,
                                              const float* __restrict__ wex3,   // [NH][NC]
                                              const float* __restrict__ wex5,   // [NH][NC]
                                              float* __restrict__ att) {        // [2][NB][NC]
    __shared__ float fs[NB][NC];
    __shared__ float fz[NB][NH];
    __shared__ float rcnt[NB];

    if (threadIdx.x < NB) {
        const int t = (int)threadIdx.x;
        rcnt[t] = 1.0f / (float)(bounds[t + 1] - bounds[t]);
    }
    __syncthreads();

    for (int i = threadIdx.x; i < NB * NC; i += 256) {
        const int b = i >> 7;
        ((float*)fs)[i] = sums[i] * rcnt[b];
    }
    __syncthreads();

    if (threadIdx.x < NB * NH) {
        const int b = threadIdx.x >> 4;
        const int h = threadIdx.x & 15;
        float z = 0.f;
        #pragma unroll 8
        for (int c = 0; c < NC; ++c) z += fs[b][c] * w_sq[c * NH + h];
        z = (z - mean[h]) * rsqrtf(var[h] + BN_EPS) * gamma[h] + beta[h];
        fz[b][h] = z > 0.f ? z : 0.f;
    }
    __syncthreads();

    for (int i = threadIdx.x; i < NB * NC; i += 256) {
        const int b = i >> 7;
        const int c = i & 127;
        float e3 = 0.f, e5 = 0.f;
        #pragma unroll
        for (int h = 0; h < NH; ++h) {
            const float zz = fz[b][h];
            e3 += zz * wex3[h * NC + c];
            e5 += zz * wex5[h * NC + c];
        }
        const float a3 = 1.f / (1.f + expf(e5 - e3));  // softmax over the 2 branches
        att[i] = a3;
        att[NB * NC + i] = 1.f - a3;
    }
}

// ---------------------------------------------------------------------------
// Pass 2: out = feat3 * a3[b] + feat5 * a5[b], boundary-driven: the per-row
// bidx load and per-row LDS gather are replaced by per-segment register
// weights (w3/w5 loop-invariant inside each segment).
// ---------------------------------------------------------------------------
__global__ __launch_bounds__(256) void k_combine(const float4* __restrict__ f3v,
                                                 const float4* __restrict__ f5v,
                                                 const int* __restrict__ bounds,
                                                 const float* __restrict__ att,
                                                 float4* __restrict__ outv) {
    __shared__ float4 a3[NB][32];
    __shared__ float4 a5[NB][32];
    __shared__ int sb[NB + 1];
    if (threadIdx.x <= NB) sb[threadIdx.x] = bounds[threadIdx.x];
    const float4* attv = (const float4*)att;
    for (int i = threadIdx.x; i < NB * 32; i += 256) {
        ((float4*)a3)[i] = attv[i];
        ((float4*)a5)[i] = attv[NB * 32 + i];
    }
    __syncthreads();

    const int lr = threadIdx.x >> 5;
    const int cv = threadIdx.x & 31;
    const int base = (int)blockIdx.x * 8 + lr;
    const int stride = NBLK * 8;

    for (int seg = 0; seg < NB; ++seg) {
        const int hi = sb[seg + 1];
        const float4 w3 = a3[seg][cv];
        const float4 w5 = a5[seg][cv];
        for (int row = sb[seg] + base; row < hi; row += stride) {
            const float4 v3 = f3v[(size_t)row * 32 + cv];
            const float4 v5 = f5v[(size_t)row * 32 + cv];
            float4 o;
            o.x = v3.x * w3.x + v5.x * w5.x;
            o.y = v3.y * w3.y + v5.y * w5.y;
            o.z = v3.z * w3.z + v5.z * w5.z;
            o.w = v3.w * w3.w + v5.w * w5.w;
            outv[(size_t)row * 32 + cv] = o;
        }
    }
}

extern "C" void kernel_launch(void* const* d_in, const int* in_sizes, int n_in,
                              void* d_out, int out_size, void* d_ws, size_t ws_size,
                              hipStream_t stream) {
    const float* f3    = (const float*)d_in[0];
    const float* f5    = (const float*)d_in[1];
    const int*   bidx  = (const int*)d_in[2];
    const float* w_sq  = (const float*)d_in[3];
    const float* gamma = (const float*)d_in[4];
    const float* beta  = (const float*)d_in[5];
    const float* mean  = (const float*)d_in[6];
    const float* var   = (const float*)d_in[7];
    const float* wex3  = (const float*)d_in[8];
    const float* wex5  = (const float*)d_in[9];
    float* out = (float*)d_out;

    const int N = in_sizes[2];                 // 500000 rows

    float* sums   = (float*)d_ws;              // [NB][NC]
    float* att    = sums + NB * NC;            // [2][NB][NC]
    int*   bounds = (int*)(att + 2 * NB * NC); // [NB+1]

    k_prep<<<1, 256, 0, stream>>>(bidx, sums, bounds, N);
    k_segsum<<<NBLK, 256, 0, stream>>>((const float4*)f3, (const float4*)f5, bounds, sums);
    k_attn<<<1, 256, 0, stream>>>(sums, bounds, w_sq, gamma, beta, mean, var, wex3, wex5, att);
    k_combine<<<NBLK, 256, 0, stream>>>((const float4*)f3, (const float4*)f5, bounds, att,
                                        (float4*)out);
}